// Round 1
// 3911.735 us; speedup vs baseline: 3.6207x; 3.6207x over previous
//
#include <hip/hip_runtime.h>

#define Hh 1024
#define Vv 512
#define Bb 128
#define Tt 512
#define TV (Tt * Vv) /* 262144 */

typedef unsigned short u16;
typedef unsigned int u32;
typedef unsigned long long u64;
typedef __attribute__((ext_vector_type(8))) short bf16x8;
typedef __attribute__((ext_vector_type(4))) float floatx4;

// ---------- ws layout (bytes) ----------
#define WS_WGA 0                    // 4*64*48*512 u16 = 12,582,912 B
#define WS_WYA 12582912             // 32*32*512 u16   =  1,048,576 B
#define WS_AF0 13631488             // 131072 u16      =    262,144 B
#define WS_AF1 13893632             // 131072 u16      =    262,144 B
#define WS_CTRL 14155776            // flags u32[4][64] = 1024 B ; +1024: loss acc

__device__ __forceinline__ u16 f2bf(float f) {
    union { float f; u32 u; } c; c.f = f;
    u32 u = c.u + 0x7fffu + ((c.u >> 16) & 1u);   // RNE
    return (u16)(u >> 16);
}
__device__ __forceinline__ float sigm(float x) { return 1.0f / (1.0f + __expf(-x)); }
__device__ __forceinline__ float tanh_f(float x) {
    float e = __expf(-2.0f * fabsf(x));
    float t = (1.0f - e) / (1.0f + e);
    return x >= 0.0f ? t : -t;
}
// coherent (agent-scope, cache-bypassing) 16B fragment load: sees remote-XCD stores
// without needing an L2-invalidating acquire fence.
__device__ __forceinline__ bf16x8 load_cohere(const u16* p) {
    union { u64 q[2]; bf16x8 v; } u;
    u64* q = (u64*)p;
    u.q[0] = __hip_atomic_load(q, __ATOMIC_RELAXED, __HIP_MEMORY_SCOPE_AGENT);
    u.q[1] = __hip_atomic_load(q + 1, __ATOMIC_RELAXED, __HIP_MEMORY_SCOPE_AGENT);
    return u.v;
}

// ---------- pack W{f,u,cc,o} (1024x1536 f32) -> [hc][kt][g] fragment-linear bf16 ----------
__global__ __launch_bounds__(256) void pack_gates(const float* __restrict__ Wf, const float* __restrict__ Wu,
                                                  const float* __restrict__ Wc, const float* __restrict__ Wo,
                                                  u16* __restrict__ WgA) {
    int tid = blockIdx.x * 256 + threadIdx.x;  // 786432 total
    int l = tid & 63;
    int q = tid >> 6;          // frag index = (hc*48 + kt)*4 + g
    int g = q & 3; q >>= 2;
    int kt = q % 48; int hc = q / 48;
    const float* W = (g == 0) ? Wf : (g == 1) ? Wu : (g == 2) ? Wc : Wo;
    int row = hc * 16 + (l & 15);
    int k = kt * 32 + (l >> 4) * 8;
    const float* src = W + (size_t)row * 1536 + k;
    float4 a = *(const float4*)src;
    float4 b = *(const float4*)(src + 4);
    bf16x8 v;
    v[0] = (short)f2bf(a.x); v[1] = (short)f2bf(a.y); v[2] = (short)f2bf(a.z); v[3] = (short)f2bf(a.w);
    v[4] = (short)f2bf(b.x); v[5] = (short)f2bf(b.y); v[6] = (short)f2bf(b.z); v[7] = (short)f2bf(b.w);
    *(bf16x8*)(WgA + (size_t)tid * 8) = v;
}

// ---------- pack Wy (512x1024 f32) -> fragment-linear bf16 ----------
__global__ __launch_bounds__(256) void pack_wy(const float* __restrict__ Wy, u16* __restrict__ WyA) {
    int tid = blockIdx.x * 256 + threadIdx.x;  // 65536 total
    int l = tid & 63;
    int q = tid >> 6;
    int kt = q & 31; int i = q >> 5;
    int row = i * 16 + (l & 15);
    int k = kt * 32 + ((l >> 4) & 3) * 8;
    const float* src = Wy + (size_t)row * 1024 + k;
    float4 a = *(const float4*)src;
    float4 b = *(const float4*)(src + 4);
    bf16x8 v;
    v[0] = (short)f2bf(a.x); v[1] = (short)f2bf(a.y); v[2] = (short)f2bf(a.z); v[3] = (short)f2bf(a.w);
    v[4] = (short)f2bf(b.x); v[5] = (short)f2bf(b.y); v[6] = (short)f2bf(b.z); v[7] = (short)f2bf(b.w);
    *(bf16x8*)(WyA + (size_t)tid * 8) = v;
}

// ---------- pack a_prev (H,B f32) -> fragment-linear bf16 a-buffer ----------
__global__ __launch_bounds__(256) void pack_a(const float* __restrict__ ap, u16* __restrict__ aF0) {
    int o = blockIdx.x * 256 + threadIdx.x;  // 131072 total
    int j = o & 7, li = (o >> 3) & 63, seg = o >> 9;
    int kt = seg >> 3, ch = seg & 7;
    int h = kt * 32 + ((li >> 4) & 3) * 8 + j;
    int b = ch * 16 + (li & 15);
    aF0[o] = f2bf(ap[(size_t)h * Bb + b]);
}

// ---------- main persistent LSTM kernel (cooperative, 256 blocks x 512 thr) ----------
// 4 independent column groups (32 cols each) of 64 blocks; group-local flag barrier.
// Fence-free exchange: a-data moves via agent-scope relaxed atomics (coherence-point
// write-through / cache-bypass loads); no threadfence => weights stay L2-resident.
__global__ __launch_bounds__(512, 2) void lstm_main(
    const float* __restrict__ X, const float* __restrict__ bfp, const float* __restrict__ bup,
    const float* __restrict__ bcp, const float* __restrict__ bop, const float* __restrict__ byp,
    const float* __restrict__ c_prev, const u16* __restrict__ WgA, const u16* __restrict__ WyA,
    u16* __restrict__ aF0, u16* __restrict__ aF1, float* __restrict__ out, u32* __restrict__ flags)
{
    __shared__ __align__(16) u16 xs[32768];     // 64 KB: x double-buffered, frag-linear
    __shared__ __align__(16) float predG[16384];// 64 KB: gate partials, 8 kt-slices
    __shared__ __align__(16) float predY[2304]; //  9 KB: y partials (stride 17)

    const int tid = threadIdx.x;
    const int bid = blockIdx.x;
    const int l = tid & 63;
    const int w = tid >> 6;        // wave 0..7 = kt-slice
    const int hc = bid & 63;       // h-chunk (16 rows); bid%8 = hc%8 -> weights XCD-local
    const int cc2 = bid >> 6;      // col chunk (32 cols) == group id
    const int c0 = cc2 * 32;
    const int fm = l & 15;
    const int fq = l >> 4;         // 0..3
    const int fk = fq * 8;
    u32* gFlags = flags + cc2 * 64;   // group-local 64 flags

    // elementwise coords
    const int em = tid >> 5;       // 0..15
    const int en = tid & 31;       // 0..31
    const int hrow = hc * 16 + em;
    const int bcol = c0 + en;
    float c_val = c_prev[(size_t)hrow * Bb + bcol];
    const float bfv = bfp[hrow], buv = bup[hrow], bcv = bcp[hrow], bov = bop[hrow];
    const int a_kt = hrow >> 5;
    const int a_q = (hrow >> 3) & 3;
    const int a_j = hrow & 7;
    const int a_ch = bcol >> 4;
    const int a_lane = (a_q << 4) | (bcol & 15);
    const int aWidx = ((a_kt << 3) + a_ch) * 512 + a_lane * 8 + a_j;
    // swizzled predG read column (write rotates col by 8*fq within row group)
    const int rcol = (en + ((em & 12) << 1)) & 31;
    // y-GEMM tile: block = (V-rowtile yi, col-half ych)
    const int yi = hc >> 1;        // 0..31
    const int ych = hc & 1;
    const int ybch = (cc2 << 1) | ych;

    floatx4 acc[4][2];             // [gate][col-chunk] partial over this wave's 6 kts
    auto zacc = [&]() {
#pragma unroll
        for (int g = 0; g < 4; ++g)
#pragma unroll
            for (int c = 0; c < 2; ++c) acc[g][c] = (floatx4){0.f, 0.f, 0.f, 0.f};
    };
    // x-part of gate GEMM for step tt (kt 32..47, LDS-only) — runs in barrier shadow
    auto xpart = [&](int tt) {
        const u16* xbuf = xs + (tt & 1) * 16384;
#pragma unroll
        for (int kk = 0; kk < 2; ++kk) {
            int ktx = (w << 1) + kk;           // 0..15
            const u16* bp = xbuf + (size_t)(ktx << 1) * 512 + (l << 3);
            bf16x8 b0 = *(const bf16x8*)bp;
            bf16x8 b1 = *(const bf16x8*)(bp + 512);
            const u16* ap = WgA + (size_t)((hc * 48 + 32 + ktx) << 2) * 512 + (l << 3);
#pragma unroll
            for (int g = 0; g < 4; ++g) {
                bf16x8 a = *(const bf16x8*)(ap + (size_t)g * 512);
                acc[g][0] = __builtin_amdgcn_mfma_f32_16x16x32_bf16(a, b0, acc[g][0], 0, 0, 0);
                acc[g][1] = __builtin_amdgcn_mfma_f32_16x16x32_bf16(a, b1, acc[g][1], 0, 0, 0);
            }
        }
    };
    auto stage_direct = [&](int tt) {
        const float* Xt = X + (size_t)tt * Vv;
        u16* xdst = xs + (tt & 1) * 16384;
#pragma unroll
        for (int it = 0; it < 4; ++it) {
            int s = w + (it << 3);
            int kt2 = s >> 1, half = s & 1;
            int b = c0 + (half << 4) + fm;
            const float* p = Xt + (size_t)b * TV + kt2 * 32 + fk;
            float4 a = *(const float4*)p;
            float4 bx = *(const float4*)(p + 4);
            bf16x8 v;
            v[0] = (short)f2bf(a.x); v[1] = (short)f2bf(a.y); v[2] = (short)f2bf(a.z); v[3] = (short)f2bf(a.w);
            v[4] = (short)f2bf(bx.x); v[5] = (short)f2bf(bx.y); v[6] = (short)f2bf(bx.z); v[7] = (short)f2bf(bx.w);
            *(bf16x8*)(xdst + s * 512 + (l << 3)) = v;
        }
    };
    auto barrier_wait = [&](u32 gen) {
        if (tid < 64) {
            while (1) {
                u32 v = __hip_atomic_load(gFlags + l, __ATOMIC_RELAXED, __HIP_MEMORY_SCOPE_AGENT);
                if (__all(v >= gen)) break;
                __builtin_amdgcn_s_sleep(2);
            }
        }
        __builtin_amdgcn_fence(__ATOMIC_ACQUIRE, "workgroup");  // compile-time order; no L2 inv
        __syncthreads();
    };

    // ---- prologue: stage x_0, x_1 ; start accs with x-part(0) ----
    stage_direct(0);
    stage_direct(1);
    __syncthreads();
    zacc();
    xpart(0);

    for (int t = 0; t < Tt; ++t) {
        if (t > 0) barrier_wait((u32)t);            // a_t ready group-wide
        const u16* aCur = (t & 1) ? aF1 : aF0;
        u16* aNxt = (t & 1) ? aF0 : aF1;

        // ---- A: gate a-part (kt = 4w..4w+3) + y-GEMM(t-1) reusing the same b-frags ----
        floatx4 yacc = {0.f, 0.f, 0.f, 0.f};
#pragma unroll
        for (int kk = 0; kk < 4; ++kk) {
            const int kt = (w << 2) + kk;
            const u16* bp = aCur + (size_t)((kt << 3) + (cc2 << 1)) * 512 + (l << 3);
            bf16x8 b0 = load_cohere(bp);
            bf16x8 b1 = load_cohere(bp + 512);
            const u16* ap = WgA + (size_t)((hc * 48 + kt) << 2) * 512 + (l << 3);
#pragma unroll
            for (int g = 0; g < 4; ++g) {
                bf16x8 a = *(const bf16x8*)(ap + (size_t)g * 512);
                acc[g][0] = __builtin_amdgcn_mfma_f32_16x16x32_bf16(a, b0, acc[g][0], 0, 0, 0);
                acc[g][1] = __builtin_amdgcn_mfma_f32_16x16x32_bf16(a, b1, acc[g][1], 0, 0, 0);
            }
            if (t > 0) {
                bf16x8 ya = *(const bf16x8*)(WyA + (size_t)(yi * 32 + kt) * 512 + (l << 3));
                if (ych) yacc = __builtin_amdgcn_mfma_f32_16x16x32_bf16(ya, b1, yacc, 0, 0, 0);
                else     yacc = __builtin_amdgcn_mfma_f32_16x16x32_bf16(ya, b0, yacc, 0, 0, 0);
            }
        }

        // ---- B: dump partials (swizzled: col rotated by 8*fq -> 2-way conflicts only) ----
        {
            float* pw = predG + w * 2048;
#pragma unroll
            for (int g = 0; g < 4; ++g)
#pragma unroll
                for (int c = 0; c < 2; ++c)
#pragma unroll
                    for (int r = 0; r < 4; ++r)
                        pw[((g << 4) + (fq << 2) + r) * 32 + (((c << 4) + fm + (fq << 3)) & 31)] = acc[g][c][r];
            if (t > 0) {
                float* py = predY + w * 272;
#pragma unroll
                for (int r = 0; r < 4; ++r) py[((fq << 2) + r) * 17 + fm] = yacc[r];
            }
        }
        __syncthreads();

        // ---- C: elementwise gates, c/a update (+ y-out for t-1) ----
        {
            float s0 = 0.f, s1 = 0.f, s2 = 0.f, s3 = 0.f;
#pragma unroll
            for (int ks = 0; ks < 8; ++ks) {
                const float* pk = predG + ks * 2048 + em * 32 + rcol;
                s0 += pk[0]; s1 += pk[512]; s2 += pk[1024]; s3 += pk[1536];
            }
            float f = sigm(s0 + bfv), u = sigm(s1 + buv);
            float ccv = tanh_f(s2 + bcv), oo = sigm(s3 + bov);
            c_val = f * c_val + u * ccv;
            float a_new = oo * tanh_f(c_val);
            u32 me = (u32)f2bf(a_new);
            u32 other = (u32)__shfl_xor((int)me, 32);
            if (l < 32) {   // even-h lane packs (even,odd) pair -> one coherent u32 store
                u32 packed = me | (other << 16);
                __hip_atomic_store((u32*)aNxt + (aWidx >> 1), packed, __ATOMIC_RELAXED, __HIP_MEMORY_SCOPE_AGENT);
            }
            if (t > 0 && tid < 256) {
                int n = tid >> 4, m = tid & 15;
                float s = 0.f;
#pragma unroll
                for (int ww = 0; ww < 8; ++ww) s += predY[ww * 272 + m * 17 + n];
                s += byp[(yi << 4) + m];
                out[(size_t)((cc2 << 5) + (ych << 4) + n) * TV + (size_t)(t - 1) * Vv + (yi << 4) + m] = s;
            }
        }
        asm volatile("s_waitcnt vmcnt(0)" ::: "memory");  // belt+braces: own stores at coherence pt
        __syncthreads();                                   // all waves' a-stores drained

        // ---- D: arrive (coherence-point store; readers' sc1 loads see data w/o fences) ----
        if (tid == 0)
            __hip_atomic_store(gFlags + hc, (u32)(t + 1), __ATOMIC_RELAXED, __HIP_MEMORY_SCOPE_AGENT);

        // ---- E/F: barrier-shadow work: issue x_{t+2} loads, x-part GEMM(t+1), LDS write ----
        float4 xr[4][2];
        const bool doStage = (t + 2 < Tt);
        if (doStage) {
            const float* Xt = X + (size_t)(t + 2) * Vv;
#pragma unroll
            for (int it = 0; it < 4; ++it) {
                int s = w + (it << 3);
                int kt2 = s >> 1, half = s & 1;
                int b = c0 + (half << 4) + fm;
                const float* p = Xt + (size_t)b * TV + kt2 * 32 + fk;
                xr[it][0] = *(const float4*)p;
                xr[it][1] = *(const float4*)(p + 4);
            }
        }
        zacc();
        if (t + 1 < Tt) xpart(t + 1);       // starts next step's accs from LDS x
        if (doStage) {                       // HBM latency hidden under xpart
            u16* xdst = xs + (t & 1) * 16384;
#pragma unroll
            for (int it = 0; it < 4; ++it) {
                int s = w + (it << 3);
                bf16x8 v;
                v[0] = (short)f2bf(xr[it][0].x); v[1] = (short)f2bf(xr[it][0].y);
                v[2] = (short)f2bf(xr[it][0].z); v[3] = (short)f2bf(xr[it][0].w);
                v[4] = (short)f2bf(xr[it][1].x); v[5] = (short)f2bf(xr[it][1].y);
                v[6] = (short)f2bf(xr[it][1].z); v[7] = (short)f2bf(xr[it][1].w);
                *(bf16x8*)(xdst + s * 512 + (l << 3)) = v;
            }
        }
    }

    // ---- epilogue: y(T-1) = Wy @ a_T ----
    barrier_wait((u32)Tt);
    {
        const u16* aCur = (Tt & 1) ? aF1 : aF0;
        floatx4 yacc = {0.f, 0.f, 0.f, 0.f};
#pragma unroll
        for (int kk = 0; kk < 4; ++kk) {
            const int kt = (w << 2) + kk;
            bf16x8 ya = *(const bf16x8*)(WyA + (size_t)(yi * 32 + kt) * 512 + (l << 3));
            bf16x8 b = load_cohere(aCur + (size_t)((kt << 3) + ybch) * 512 + (l << 3));
            yacc = __builtin_amdgcn_mfma_f32_16x16x32_bf16(ya, b, yacc, 0, 0, 0);
        }
        float* py = predY + w * 272;
#pragma unroll
        for (int r = 0; r < 4; ++r) py[((fq << 2) + r) * 17 + fm] = yacc[r];
        __syncthreads();
        if (tid < 256) {
            int n = tid >> 4, m = tid & 15;
            float s = 0.f;
#pragma unroll
            for (int ww = 0; ww < 8; ++ww) s += predY[ww * 272 + m * 17 + n];
            s += byp[(yi << 4) + m];
            out[(size_t)((cc2 << 5) + (ych << 4) + n) * TV + (size_t)(Tt - 1) * Vv + (yi << 4) + m] = s;
        }
    }
}

// ---------- CE loss ----------
__global__ __launch_bounds__(256) void loss_k(const float* __restrict__ logits, const int* __restrict__ Y,
                                              float* __restrict__ acc) {
    int w = threadIdx.x >> 6, l = threadIdx.x & 63;
    int rbase = blockIdx.x * 256 + w * 64;
    float sum = 0.f;
    for (int i = 0; i < 64; ++i) {
        const float* row = logits + (size_t)(rbase + i) * Vv;
        float4 v0 = *(const float4*)(row + l * 8);
        float4 v1 = *(const float4*)(row + l * 8 + 4);
        float vals[8] = {v0.x, v0.y, v0.z, v0.w, v1.x, v1.y, v1.z, v1.w};
        float mx = vals[0];
#pragma unroll
        for (int j = 1; j < 8; ++j) mx = fmaxf(mx, vals[j]);
#pragma unroll
        for (int s = 1; s < 64; s <<= 1) mx = fmaxf(mx, __shfl_xor(mx, s, 64));
        float es = 0.f;
#pragma unroll
        for (int j = 0; j < 8; ++j) es += __expf(vals[j] - mx);
#pragma unroll
        for (int s = 1; s < 64; s <<= 1) es += __shfl_xor(es, s, 64);
        int label = Y[rbase + i];
        float xl_local = vals[0];
#pragma unroll
        for (int j = 1; j < 8; ++j) xl_local = ((label & 7) == j) ? vals[j] : xl_local;
        float xl = __shfl(xl_local, label >> 3, 64);
        sum += (mx + __logf(es)) - xl;
    }
    if (l == 0) atomicAdd(acc, sum);
}

__global__ void finalize_k(const float* __restrict__ acc, float* __restrict__ out) {
    if (threadIdx.x == 0) out[(size_t)Bb * Tt * Vv] = acc[0] * (1.0f / (Bb * Tt));
}

extern "C" void kernel_launch(void* const* d_in, const int* in_sizes, int n_in,
                              void* d_out, int out_size, void* d_ws, size_t ws_size,
                              hipStream_t stream) {
    const float* X  = (const float*)d_in[0];
    const int*   Y  = (const int*)d_in[1];
    const float* Wf = (const float*)d_in[2];
    const float* bf = (const float*)d_in[3];
    const float* Wu = (const float*)d_in[4];
    const float* bu = (const float*)d_in[5];
    const float* Wc = (const float*)d_in[6];
    const float* bc = (const float*)d_in[7];
    const float* Wo = (const float*)d_in[8];
    const float* bo = (const float*)d_in[9];
    const float* Wy = (const float*)d_in[10];
    const float* by = (const float*)d_in[11];
    const float* ap = (const float*)d_in[12];
    const float* cp = (const float*)d_in[13];
    float* out = (float*)d_out;
    char* ws = (char*)d_ws;
    u16* WgA = (u16*)(ws + WS_WGA);
    u16* WyA = (u16*)(ws + WS_WYA);
    u16* aF0 = (u16*)(ws + WS_AF0);
    u16* aF1 = (u16*)(ws + WS_AF1);
    u32* flags = (u32*)(ws + WS_CTRL);
    float* lossAcc = (float*)(ws + WS_CTRL + 1024);

    hipMemsetAsync((void*)flags, 0, 2048, stream);
    pack_gates<<<3072, 256, 0, stream>>>(Wf, Wu, Wc, Wo, WgA);
    pack_wy<<<256, 256, 0, stream>>>(Wy, WyA);
    pack_a<<<512, 256, 0, stream>>>(ap, aF0);

    void* args[] = {(void*)&X, (void*)&bf, (void*)&bu, (void*)&bc, (void*)&bo, (void*)&by,
                    (void*)&cp, (void*)&WgA, (void*)&WyA, (void*)&aF0, (void*)&aF1,
                    (void*)&out, (void*)&flags};
    hipLaunchCooperativeKernel((void*)lstm_main, dim3(256), dim3(512), args, 0, stream);

    loss_k<<<256, 256, 0, stream>>>(out, Y, lossAcc);
    finalize_k<<<1, 64, 0, stream>>>(lossAcc, out);
}

// Round 3
// 3632.865 us; speedup vs baseline: 3.8986x; 1.0768x over previous
//
#include <hip/hip_runtime.h>

#define Hh 1024
#define Vv 512
#define Bb 128
#define Tt 512
#define TV (Tt * Vv) /* 262144 */

typedef unsigned short u16;
typedef unsigned int u32;
typedef unsigned long long u64;
typedef __attribute__((ext_vector_type(8))) short bf16x8;
typedef __attribute__((ext_vector_type(4))) float floatx4;

// ---------- ws layout (bytes) ----------
#define WS_WGA 0                    // 4*64*48*512 u16 = 12,582,912 B
#define WS_WYA 12582912             // 32*32*512 u16   =  1,048,576 B
#define WS_AF0 13631488             // 131072 u16      =    262,144 B
#define WS_AF1 13893632             // 131072 u16      =    262,144 B
#define WS_CTRL 14155776            // flags u32[4][64] = 1024 B ; +1024: loss acc

__device__ __forceinline__ u16 f2bf(float f) {
    union { float f; u32 u; } c; c.f = f;
    u32 u = c.u + 0x7fffu + ((c.u >> 16) & 1u);   // RNE
    return (u16)(u >> 16);
}
__device__ __forceinline__ float sigm(float x) { return 1.0f / (1.0f + __expf(-x)); }
__device__ __forceinline__ float tanh_f(float x) {
    float e = __expf(-2.0f * fabsf(x));
    float t = (1.0f - e) / (1.0f + e);
    return x >= 0.0f ? t : -t;
}
// coherent (agent-scope, cache-bypassing) 16B fragment load: sees remote-XCD stores
// without an L2-invalidating acquire fence (weights stay L2-resident).
__device__ __forceinline__ bf16x8 load_cohere(const u16* p) {
    union { u64 q[2]; bf16x8 v; } u;
    u64* q = (u64*)p;
    u.q[0] = __hip_atomic_load(q, __ATOMIC_RELAXED, __HIP_MEMORY_SCOPE_AGENT);
    u.q[1] = __hip_atomic_load(q + 1, __ATOMIC_RELAXED, __HIP_MEMORY_SCOPE_AGENT);
    return u.v;
}

// ---------- pack W{f,u,cc,o} (1024x1536 f32) -> [hc][kt][g] fragment-linear bf16 ----------
__global__ __launch_bounds__(256) void pack_gates(const float* __restrict__ Wf, const float* __restrict__ Wu,
                                                  const float* __restrict__ Wc, const float* __restrict__ Wo,
                                                  u16* __restrict__ WgA) {
    int tid = blockIdx.x * 256 + threadIdx.x;  // 786432 total
    int l = tid & 63;
    int q = tid >> 6;          // frag index = (hc*48 + kt)*4 + g
    int g = q & 3; q >>= 2;
    int kt = q % 48; int hc = q / 48;
    const float* W = (g == 0) ? Wf : (g == 1) ? Wu : (g == 2) ? Wc : Wo;
    int row = hc * 16 + (l & 15);
    int k = kt * 32 + (l >> 4) * 8;
    const float* src = W + (size_t)row * 1536 + k;
    float4 a = *(const float4*)src;
    float4 b = *(const float4*)(src + 4);
    bf16x8 v;
    v[0] = (short)f2bf(a.x); v[1] = (short)f2bf(a.y); v[2] = (short)f2bf(a.z); v[3] = (short)f2bf(a.w);
    v[4] = (short)f2bf(b.x); v[5] = (short)f2bf(b.y); v[6] = (short)f2bf(b.z); v[7] = (short)f2bf(b.w);
    *(bf16x8*)(WgA + (size_t)tid * 8) = v;
}

// ---------- pack Wy (512x1024 f32) -> fragment-linear bf16 ----------
__global__ __launch_bounds__(256) void pack_wy(const float* __restrict__ Wy, u16* __restrict__ WyA) {
    int tid = blockIdx.x * 256 + threadIdx.x;  // 65536 total
    int l = tid & 63;
    int q = tid >> 6;
    int kt = q & 31; int i = q >> 5;
    int row = i * 16 + (l & 15);
    int k = kt * 32 + ((l >> 4) & 3) * 8;
    const float* src = Wy + (size_t)row * 1024 + k;
    float4 a = *(const float4*)src;
    float4 b = *(const float4*)(src + 4);
    bf16x8 v;
    v[0] = (short)f2bf(a.x); v[1] = (short)f2bf(a.y); v[2] = (short)f2bf(a.z); v[3] = (short)f2bf(a.w);
    v[4] = (short)f2bf(b.x); v[5] = (short)f2bf(b.y); v[6] = (short)f2bf(b.z); v[7] = (short)f2bf(b.w);
    *(bf16x8*)(WyA + (size_t)tid * 8) = v;
}

// ---------- pack a_prev (H,B f32) -> fragment-linear bf16 a-buffer ----------
__global__ __launch_bounds__(256) void pack_a(const float* __restrict__ ap, u16* __restrict__ aF0) {
    int o = blockIdx.x * 256 + threadIdx.x;  // 131072 total
    int j = o & 7, li = (o >> 3) & 63, seg = o >> 9;
    int kt = seg >> 3, ch = seg & 7;
    int h = kt * 32 + ((li >> 4) & 3) * 8 + j;
    int b = ch * 16 + (li & 15);
    aF0[o] = f2bf(ap[(size_t)h * Bb + b]);
}

// ---------- main persistent LSTM kernel (cooperative, 256 blocks x 512 thr) ----------
// 4 independent column groups (32 cols each) of 64 blocks.
// PER-WAVE flag waits: wave w consumes only kt 4w..4w+3 -> producer blocks hc 8w..8w+7.
// WAR safety: phase-C stores are behind sync1, which joins all 8 waves whose wait
// sets union to all 64 flags (every group block finished its previous-step reads).
__global__ __launch_bounds__(512, 2) void lstm_main(
    const float* __restrict__ X, const float* __restrict__ bfp, const float* __restrict__ bup,
    const float* __restrict__ bcp, const float* __restrict__ bop, const float* __restrict__ byp,
    const float* __restrict__ c_prev, const u16* __restrict__ WgA, const u16* __restrict__ WyA,
    u16* __restrict__ aF0, u16* __restrict__ aF1, float* __restrict__ out, u32* __restrict__ flags)
{
    __shared__ __align__(16) u16 xs[32768];     // 64 KB: x double-buffered, frag-linear
    __shared__ __align__(16) float predG[16384];// 64 KB: gate partials, 8 kt-slices
    __shared__ __align__(16) float predY[2304]; //  9 KB: y partials (stride 17)

    const int tid = threadIdx.x;
    const int bid = blockIdx.x;
    const int l = tid & 63;
    const int w = tid >> 6;        // wave 0..7 = kt-slice
    const int hc = bid & 63;       // h-chunk (16 rows); bid%8 = hc%8 -> weights XCD-local
    const int grp = bid >> 6;      // col group id
    const int cc2 = grp;
    const int c0 = cc2 * 32;
    const int fm = l & 15;
    const int fq = l >> 4;         // 0..3
    u32* gFlags = flags + cc2 * 64;   // group-local 64 flags

    // elementwise coords
    const int em = tid >> 5;       // 0..15
    const int en = tid & 31;       // 0..31
    const int hrow = (hc << 4) + em;
    const int bcol = c0 + en;
    float c_val = c_prev[(size_t)hrow * Bb + bcol];
    const float bfv = bfp[hrow], buv = bup[hrow], bcv = bcp[hrow], bov = bop[hrow];
    const int a_kt = hrow >> 5;
    const int a_q = (hrow >> 3) & 3;
    const int a_j = hrow & 7;
    const int a_ch = bcol >> 4;
    const int a_lane = (a_q << 4) | (bcol & 15);
    const int aWidx = ((a_kt << 3) + a_ch) * 512 + a_lane * 8 + a_j;
    // swizzled predG read column (write rotates col by 8*fq within row group)
    const int rcol = (en + ((em & 12) << 1)) & 31;
    // y-GEMM tile: block = (V-rowtile yi, col-half ych)
    const int yi = hc >> 1;        // 0..31
    const int ych = hc & 1;
    const int ybch = (cc2 << 1) | ych;

    floatx4 acc[4][2];             // [gate][col-chunk] partial over this wave's kts
    auto zacc = [&]() {
#pragma unroll
        for (int g = 0; g < 4; ++g)
#pragma unroll
            for (int c = 0; c < 2; ++c) acc[g][c] = (floatx4){0.f, 0.f, 0.f, 0.f};
    };
    // x-part of gate GEMM for step tt (kt 32..47, LDS-only) — runs in flag shadow
    auto xpart = [&](int tt) {
        const u16* xbuf = xs + (tt & 1) * 16384;
#pragma unroll
        for (int kk = 0; kk < 2; ++kk) {
            int ktx = (w << 1) + kk;           // 0..15
            const u16* bp = xbuf + (size_t)(ktx << 1) * 512 + (l << 3);
            bf16x8 b0 = *(const bf16x8*)bp;
            bf16x8 b1 = *(const bf16x8*)(bp + 512);
            const u16* ap = WgA + (size_t)((hc * 48 + 32 + ktx) << 2) * 512 + (l << 3);
#pragma unroll
            for (int g = 0; g < 4; ++g) {
                bf16x8 a = *(const bf16x8*)(ap + (size_t)g * 512);
                acc[g][0] = __builtin_amdgcn_mfma_f32_16x16x32_bf16(a, b0, acc[g][0], 0, 0, 0);
                acc[g][1] = __builtin_amdgcn_mfma_f32_16x16x32_bf16(a, b1, acc[g][1], 0, 0, 0);
            }
        }
    };
    auto stage_direct = [&](int tt) {
        const float* Xt = X + (size_t)tt * Vv;
        u16* xdst = xs + (tt & 1) * 16384;
#pragma unroll
        for (int it = 0; it < 4; ++it) {
            int s = w + (it << 3);
            int kt2 = s >> 1, half = s & 1;
            int b = c0 + (half << 4) + fm;
            const float* p = Xt + (size_t)b * TV + kt2 * 32 + (fq << 3);
            float4 a = *(const float4*)p;
            float4 bx = *(const float4*)(p + 4);
            bf16x8 v;
            v[0] = (short)f2bf(a.x); v[1] = (short)f2bf(a.y); v[2] = (short)f2bf(a.z); v[3] = (short)f2bf(a.w);
            v[4] = (short)f2bf(bx.x); v[5] = (short)f2bf(bx.y); v[6] = (short)f2bf(bx.z); v[7] = (short)f2bf(bx.w);
            *(bf16x8*)(xdst + s * 512 + (l << 3)) = v;
        }
    };
    // per-wave wait: wave w's kt slice (4w..4w+3) sources blocks hc=8w..8w+7 only
    auto wave_wait = [&](u32 gen) {
        const u32 src = (u32)((w << 3) + (l & 7));
        while (1) {
            u32 v = __hip_atomic_load(gFlags + src, __ATOMIC_RELAXED, __HIP_MEMORY_SCOPE_AGENT);
            if (__all(v >= gen)) break;
            __builtin_amdgcn_s_sleep(2);
        }
        __builtin_amdgcn_fence(__ATOMIC_ACQUIRE, "workgroup");  // compile-time order; no L2 inv
    };

    // ---- prologue: stage x_0, x_1 ; start accs with x-part(0) ----
    stage_direct(0);
    stage_direct(1);
    __syncthreads();
    zacc();
    xpart(0);

    for (int t = 0; t < Tt; ++t) {
        const u16* aCur = (t & 1) ? aF1 : aF0;
        u16* aNxt = (t & 1) ? aF0 : aF1;
        if (t > 0) wave_wait((u32)t);

        // ---- A: gate a-part (kt = 4w..4w+3); save this block's y-chunk fragments ----
        bf16x8 bsel[4];
#pragma unroll
        for (int kk = 0; kk < 4; ++kk) {
            const int kt = (w << 2) + kk;
            const u16* bp = aCur + (size_t)((kt << 3) + (cc2 << 1)) * 512 + (l << 3);
            bf16x8 b0 = load_cohere(bp);
            bf16x8 b1 = load_cohere(bp + 512);
            bsel[kk] = ych ? b1 : b0;
            const u16* ap = WgA + (size_t)((hc * 48 + kt) << 2) * 512 + (l << 3);
#pragma unroll
            for (int g = 0; g < 4; ++g) {
                bf16x8 a = *(const bf16x8*)(ap + (size_t)g * 512);
                acc[g][0] = __builtin_amdgcn_mfma_f32_16x16x32_bf16(a, b0, acc[g][0], 0, 0, 0);
                acc[g][1] = __builtin_amdgcn_mfma_f32_16x16x32_bf16(a, b1, acc[g][1], 0, 0, 0);
            }
        }

        // ---- B: dump partials (swizzled: col rotated by 8*fq -> 2-way conflicts only) ----
        {
            float* pw = predG + w * 2048;
#pragma unroll
            for (int g = 0; g < 4; ++g)
#pragma unroll
                for (int c = 0; c < 2; ++c)
#pragma unroll
                    for (int r = 0; r < 4; ++r)
                        pw[((g << 4) + (fq << 2) + r) * 32 + (((c << 4) + fm + (fq << 3)) & 31)] = acc[g][c][r];
        }
        __syncthreads();  // sync1

        // ---- C: elementwise gates, c/a update, packed coherent a-store ----
        {
            float s0 = 0.f, s1 = 0.f, s2 = 0.f, s3 = 0.f;
#pragma unroll
            for (int ks = 0; ks < 8; ++ks) {
                const float* pk = predG + ks * 2048 + em * 32 + rcol;
                s0 += pk[0]; s1 += pk[512]; s2 += pk[1024]; s3 += pk[1536];
            }
            float f = sigm(s0 + bfv), u = sigm(s1 + buv);
            float ccv = tanh_f(s2 + bcv), oo = sigm(s3 + bov);
            c_val = f * c_val + u * ccv;
            float a_new = oo * tanh_f(c_val);
            u32 me = (u32)f2bf(a_new);
            u32 other = (u32)__shfl_xor((int)me, 32);       // partner em^1 (same wave)
            if (l < 32)
                __hip_atomic_store((u32*)aNxt + (aWidx >> 1), me | (other << 16),
                                   __ATOMIC_RELAXED, __HIP_MEMORY_SCOPE_AGENT);
        }
        asm volatile("s_waitcnt vmcnt(0)" ::: "memory");  // a-stores at coherence point
        __syncthreads();   // sync2: all waves' a-stores drained
        if (tid == 0)
            __hip_atomic_store(gFlags + hc, (u32)(t + 1), __ATOMIC_RELAXED, __HIP_MEMORY_SCOPE_AGENT);

        // ---- shadow (post-flag): x issue, y-GEMM on saved frags, xpart(t+1), x write ----
        float4 xr[4][2];
        const bool doStage = (t + 2 < Tt);
        if (doStage) {
            const float* Xt = X + (size_t)(t + 2) * Vv;
#pragma unroll
            for (int it = 0; it < 4; ++it) {
                int s = w + (it << 3);
                int kt2 = s >> 1, half = s & 1;
                int b = c0 + (half << 4) + fm;
                const float* p = Xt + (size_t)b * TV + kt2 * 32 + (fq << 3);
                xr[it][0] = *(const float4*)p;
                xr[it][1] = *(const float4*)(p + 4);
            }
        }
        if (t > 0) {
            floatx4 yacc = {0.f, 0.f, 0.f, 0.f};
#pragma unroll
            for (int kk = 0; kk < 4; ++kk) {
                const int kt = (w << 2) + kk;
                bf16x8 ya = *(const bf16x8*)(WyA + (size_t)(yi * 32 + kt) * 512 + (l << 3));
                yacc = __builtin_amdgcn_mfma_f32_16x16x32_bf16(ya, bsel[kk], yacc, 0, 0, 0);
            }
            float* py = predY + w * 272;
#pragma unroll
            for (int r = 0; r < 4; ++r) py[((fq << 2) + r) * 17 + fm] = yacc[r];
        }
        zacc();
        if (t + 1 < Tt) xpart(t + 1);
        if (doStage) {                       // HBM latency hidden under y/xpart
            u16* xdst = xs + (t & 1) * 16384;
#pragma unroll
            for (int it = 0; it < 4; ++it) {
                int s = w + (it << 3);
                bf16x8 v;
                v[0] = (short)f2bf(xr[it][0].x); v[1] = (short)f2bf(xr[it][0].y);
                v[2] = (short)f2bf(xr[it][0].z); v[3] = (short)f2bf(xr[it][0].w);
                v[4] = (short)f2bf(xr[it][1].x); v[5] = (short)f2bf(xr[it][1].y);
                v[6] = (short)f2bf(xr[it][1].z); v[7] = (short)f2bf(xr[it][1].w);
                *(bf16x8*)(xdst + s * 512 + (l << 3)) = v;
            }
        }
        __syncthreads();   // sync3: predY complete; xs writes ordered vs next reads
        if (t > 0 && tid < 256) {
            int n = tid >> 4, m = tid & 15;
            float s = 0.f;
#pragma unroll
            for (int ww = 0; ww < 8; ++ww) s += predY[ww * 272 + m * 17 + n];
            s += byp[(yi << 4) + m];
            out[(size_t)((cc2 << 5) + (ych << 4) + n) * TV + (size_t)(t - 1) * Vv + (yi << 4) + m] = s;
        }
    }

    // ---- epilogue: y(T-1) = Wy @ a_T ----
    wave_wait((u32)Tt);
    __syncthreads();       // protect predY vs last loop's y-out reads
    {
        const u16* aCur = (Tt & 1) ? aF1 : aF0;
        floatx4 yacc = {0.f, 0.f, 0.f, 0.f};
#pragma unroll
        for (int kk = 0; kk < 4; ++kk) {
            const int kt = (w << 2) + kk;
            bf16x8 b0 = load_cohere(aCur + (size_t)((kt << 3) + ybch) * 512 + (l << 3));
            bf16x8 ya = *(const bf16x8*)(WyA + (size_t)(yi * 32 + kt) * 512 + (l << 3));
            yacc = __builtin_amdgcn_mfma_f32_16x16x32_bf16(ya, b0, yacc, 0, 0, 0);
        }
        float* py = predY + w * 272;
#pragma unroll
        for (int r = 0; r < 4; ++r) py[((fq << 2) + r) * 17 + fm] = yacc[r];
        __syncthreads();
        if (tid < 256) {
            int n = tid >> 4, m = tid & 15;
            float s = 0.f;
#pragma unroll
            for (int ww = 0; ww < 8; ++ww) s += predY[ww * 272 + m * 17 + n];
            s += byp[(yi << 4) + m];
            out[(size_t)((cc2 << 5) + (ych << 4) + n) * TV + (size_t)(Tt - 1) * Vv + (yi << 4) + m] = s;
        }
    }
}

// ---------- CE loss ----------
__global__ __launch_bounds__(256) void loss_k(const float* __restrict__ logits, const int* __restrict__ Y,
                                              float* __restrict__ acc) {
    int w = threadIdx.x >> 6, l = threadIdx.x & 63;
    int rbase = blockIdx.x * 256 + w * 64;
    float sum = 0.f;
    for (int i = 0; i < 64; ++i) {
        const float* row = logits + (size_t)(rbase + i) * Vv;
        float4 v0 = *(const float4*)(row + l * 8);
        float4 v1 = *(const float4*)(row + l * 8 + 4);
        float vals[8] = {v0.x, v0.y, v0.z, v0.w, v1.x, v1.y, v1.z, v1.w};
        float mx = vals[0];
#pragma unroll
        for (int j = 1; j < 8; ++j) mx = fmaxf(mx, vals[j]);
#pragma unroll
        for (int s = 1; s < 64; s <<= 1) mx = fmaxf(mx, __shfl_xor(mx, s, 64));
        float es = 0.f;
#pragma unroll
        for (int j = 0; j < 8; ++j) es += __expf(vals[j] - mx);
#pragma unroll
        for (int s = 1; s < 64; s <<= 1) es += __shfl_xor(es, s, 64);
        int label = Y[rbase + i];
        float xl_local = vals[0];
#pragma unroll
        for (int j = 1; j < 8; ++j) xl_local = ((label & 7) == j) ? vals[j] : xl_local;
        float xl = __shfl(xl_local, label >> 3, 64);
        sum += (mx + __logf(es)) - xl;
    }
    if (l == 0) atomicAdd(acc, sum);
}

__global__ void finalize_k(const float* __restrict__ acc, float* __restrict__ out) {
    if (threadIdx.x == 0) out[(size_t)Bb * Tt * Vv] = acc[0] * (1.0f / (Bb * Tt));
}

extern "C" void kernel_launch(void* const* d_in, const int* in_sizes, int n_in,
                              void* d_out, int out_size, void* d_ws, size_t ws_size,
                              hipStream_t stream) {
    const float* X  = (const float*)d_in[0];
    const int*   Y  = (const int*)d_in[1];
    const float* Wf = (const float*)d_in[2];
    const float* bf = (const float*)d_in[3];
    const float* Wu = (const float*)d_in[4];
    const float* bu = (const float*)d_in[5];
    const float* Wc = (const float*)d_in[6];
    const float* bc = (const float*)d_in[7];
    const float* Wo = (const float*)d_in[8];
    const float* bo = (const float*)d_in[9];
    const float* Wy = (const float*)d_in[10];
    const float* by = (const float*)d_in[11];
    const float* ap = (const float*)d_in[12];
    const float* cp = (const float*)d_in[13];
    float* out = (float*)d_out;
    char* ws = (char*)d_ws;
    u16* WgA = (u16*)(ws + WS_WGA);
    u16* WyA = (u16*)(ws + WS_WYA);
    u16* aF0 = (u16*)(ws + WS_AF0);
    u16* aF1 = (u16*)(ws + WS_AF1);
    u32* flags = (u32*)(ws + WS_CTRL);
    float* lossAcc = (float*)(ws + WS_CTRL + 1024);

    hipMemsetAsync((void*)flags, 0, 2048, stream);
    pack_gates<<<3072, 256, 0, stream>>>(Wf, Wu, Wc, Wo, WgA);
    pack_wy<<<256, 256, 0, stream>>>(Wy, WyA);
    pack_a<<<512, 256, 0, stream>>>(ap, aF0);

    void* args[] = {(void*)&X, (void*)&bf, (void*)&bu, (void*)&bc, (void*)&bo, (void*)&by,
                    (void*)&cp, (void*)&WgA, (void*)&WyA, (void*)&aF0, (void*)&aF1,
                    (void*)&out, (void*)&flags};
    hipLaunchCooperativeKernel((void*)lstm_main, dim3(256), dim3(512), args, 0, stream);

    loss_k<<<256, 256, 0, stream>>>(out, Y, lossAcc);
    finalize_k<<<1, 64, 0, stream>>>(lossAcc, out);
}